// Round 14
// baseline (243.553 us; speedup 1.0000x reference)
//
#include <hip/hip_runtime.h>
#include <stdint.h>

#define B_  4
#define S_  2048
#define E_  1024
#define H_  16
#define D_  64

typedef __bf16 bf16;
typedef __bf16 bf16x4 __attribute__((ext_vector_type(4)));
typedef __bf16 bf16x8 __attribute__((ext_vector_type(8)));
typedef float  f32x4 __attribute__((ext_vector_type(4)));
typedef float  f32x16 __attribute__((ext_vector_type(16)));
typedef uint32_t u32x4 __attribute__((ext_vector_type(4)));

__device__ __forceinline__ f32x4 mfma16(bf16x8 a, bf16x8 b, f32x4 c) {
  return __builtin_amdgcn_mfma_f32_16x16x32_bf16(a, b, c, 0, 0, 0);
}
__device__ __forceinline__ f32x16 mfma32(bf16x8 a, bf16x8 b, f32x16 c) {
  return __builtin_amdgcn_mfma_f32_32x32x16_bf16(a, b, c, 0, 0, 0);
}

// bf16 swizzle (128B rows, 8 chunks of 8 bf16): chunk ^= row&7 (halfword units)
__device__ __forceinline__ int sw(int row, int idx) { return idx ^ ((row & 7) << 3); }

__device__ __forceinline__ void gl_lds16(const void* g, void* l) {
  __builtin_amdgcn_global_load_lds(
      (const __attribute__((address_space(1))) void*)g,
      (__attribute__((address_space(3))) void*)l, 16, 0, 0);
}

__device__ __forceinline__ uint32_t cvtpk(float lo, float hi) {
  uint32_t r;
  asm("v_cvt_pk_bf16_f32 %0, %1, %2" : "=v"(r) : "v"(lo), "v"(hi));
  return r;
}
__device__ __forceinline__ void plswap(uint32_t& a, uint32_t& b) {
  asm("v_permlane32_swap_b32 %0, %1" : "+v"(a), "+v"(b));
}

// ---------------- mask packing ----------------
__global__ void pack_mask_kernel(const int* __restrict__ mask, uint32_t* __restrict__ mbits) {
  int idx = blockIdx.x * 256 + threadIdx.x;
  int q = idx >> 6, w = idx & 63;
  const int* p = mask + q * S_ + w * 32;
  uint32_t bits = 0;
#pragma unroll
  for (int j = 0; j < 32; j += 4) {
    int4 v = *(const int4*)(p + j);
    bits |= (v.x != 0 ? 1u : 0u) << (j + 0);
    bits |= (v.y != 0 ? 1u : 0u) << (j + 1);
    bits |= (v.z != 0 ? 1u : 0u) << (j + 2);
    bits |= (v.w != 0 ? 1u : 0u) << (j + 3);
  }
  mbits[idx] = bits;
}

__global__ void pack_pad_kernel(const int* __restrict__ pad, uint32_t* __restrict__ pbits) {
  int idx = threadIdx.x;
  int b = idx >> 6, w = idx & 63;
  const int* p = pad + b * S_ + w * 32;
  uint32_t bits = 0;
#pragma unroll
  for (int j = 0; j < 32; j += 4) {
    int4 v = *(const int4*)(p + j);
    bits |= (v.x != 0 ? 1u : 0u) << (j + 0);
    bits |= (v.y != 0 ? 1u : 0u) << (j + 1);
    bits |= (v.z != 0 ? 1u : 0u) << (j + 2);
    bits |= (v.w != 0 ? 1u : 0u) << (j + 3);
  }
  pbits[idx] = bits;
}

// transpose + pre-AND pad: mbt[b][kt][q] = {mbits[q][2kt]&pad, mbits[q][2kt+1]&pad}
__global__ __launch_bounds__(256)
void expand_mask(const uint32_t* __restrict__ mbits, const uint32_t* __restrict__ pbits,
                 uint2* __restrict__ mbt) {
  int idx = blockIdx.x * 256 + threadIdx.x;   // b(4) x kt(32) x q(2048)
  int q = idx & 2047;
  int kt = (idx >> 11) & 31;
  int b = idx >> 16;
  uint2 r;
  r.x = mbits[q * 64 + kt * 2 + 0] & pbits[b * 64 + kt * 2 + 0];
  r.y = mbits[q * 64 + kt * 2 + 1] & pbits[b * 64 + kt * 2 + 1];
  mbt[idx] = r;
}

// ---------------- fp32 -> bf16 weight convert ----------------
__global__ __launch_bounds__(256)
void cvt_w(const float* __restrict__ w0, const float* __restrict__ w1,
           const float* __restrict__ w2, const float* __restrict__ w3,
           bf16* __restrict__ out, float sq, float sk) {
  int z = blockIdx.z;
  const float* src = z == 0 ? w0 : (z == 1 ? w1 : (z == 2 ? w2 : w3));
  float s = (z == 0) ? sq : ((z == 1) ? sk : 1.0f);
  size_t i = ((size_t)blockIdx.x * 256 + threadIdx.x) * 8;
  float4 a = *(const float4*)(src + i);
  float4 b = *(const float4*)(src + i + 4);
  bf16x8 o;
  o[0] = (bf16)(a.x * s); o[1] = (bf16)(a.y * s); o[2] = (bf16)(a.z * s); o[3] = (bf16)(a.w * s);
  o[4] = (bf16)(b.x * s); o[5] = (bf16)(b.y * s); o[6] = (bf16)(b.z * s); o[7] = (bf16)(b.w * s);
  *(bf16x8*)(out + (size_t)z * (1024ull * 1024ull) + i) = o;
}

// ---------------- GEMM: C = A @ W^T, fully reg-staged (never-drain) ----------------
// Both operands: global -> regs (issued one K-step early, covered by MFMA phase)
//                -> swizzled ds_write after barrier-1. Barrier-2 waits lgkm only.
// grid.x = 512 flat, XCD-chunked: xcd k owns row panels [k*8,(k+1)*8) x 8 col panels.
struct GA { const void* A; const bf16* W; void* O; };

template<bool A_F32, bool OUT_F32>
__global__ __launch_bounds__(256, 4)
void gemm_bf(GA g0, GA g1, GA g2) {
  GA g = (blockIdx.z == 0) ? g0 : ((blockIdx.z == 1) ? g1 : g2);
  const int id = blockIdx.x;
  const int brow = ((id & 7) * 8 + (id >> 6)) * 128;
  const int bcol = ((id >> 3) & 7) * 128;
  const int tid = threadIdx.x;
  const int l = tid & 63, wv = tid >> 6;
  const int lg = l >> 4, lr = l & 15;
  const int wr = wv >> 1, wc = wv & 1;
  const int sr = l >> 3, sc8 = l & 7;
  const int NT = E_ / 64;

  __shared__ __align__(16) char smem[32768];
  bf16* As = (bf16*)smem;              // 128 x 64 bf16, swizzled
  bf16* Bs = (bf16*)(smem + 16384);    // 128 x 64 bf16, swizzled

  f32x4 acc[4][4] = {};

  // ---- B staging: linear global read, swizzled ds_write ----
  const bf16* Bp = g.W + (size_t)(bcol + wv * 32 + sr) * E_ + sc8 * 8;
  bf16x8 breg[4];
  auto loadB = [&]() {
#pragma unroll
    for (int i = 0; i < 4; ++i)
      breg[i] = *(const bf16x8*)(Bp + (size_t)(8 * i) * E_);
    Bp += 64;
  };
  auto writeB = [&]() {
#pragma unroll
    for (int i = 0; i < 4; ++i) {
      int row = wv * 32 + sr + 8 * i;
      *(bf16x8*)&Bs[sw(row, row * 64 + sc8 * 8)] = breg[i];
    }
  };

  // ---- A staging: fp32 (load+cvtpk) or bf16 (load), swizzled ds_write ----
  const float* Ap = nullptr;
  const bf16*  Abp = nullptr;
  f32x4 a0[4], a1[4];
  bf16x8 areg[4];
  if constexpr (A_F32) {
    Ap = (const float*)g.A + (size_t)(brow + wv * 32 + sr) * E_ + sc8 * 8;
  } else {
    Abp = (const bf16*)g.A + (size_t)(brow + wv * 32 + sr) * E_ + sc8 * 8;
  }
  auto loadA = [&]() {
    if constexpr (A_F32) {
#pragma unroll
      for (int i = 0; i < 4; ++i) {
        const float* p = Ap + (size_t)(8 * i) * E_;
        a0[i] = *(const f32x4*)p;
        a1[i] = *(const f32x4*)(p + 4);
      }
      Ap += 64;
    } else {
#pragma unroll
      for (int i = 0; i < 4; ++i)
        areg[i] = *(const bf16x8*)(Abp + (size_t)(8 * i) * E_);
      Abp += 64;
    }
  };
  auto writeA = [&]() {
#pragma unroll
    for (int i = 0; i < 4; ++i) {
      int row = wv * 32 + sr + 8 * i;
      if constexpr (A_F32) {
        u32x4 pk = { cvtpk(a0[i][0], a0[i][1]), cvtpk(a0[i][2], a0[i][3]),
                     cvtpk(a1[i][0], a1[i][1]), cvtpk(a1[i][2], a1[i][3]) };
        *(bf16x8*)&As[sw(row, row * 64 + sc8 * 8)] = __builtin_bit_cast(bf16x8, pk);
      } else {
        *(bf16x8*)&As[sw(row, row * 64 + sc8 * 8)] = areg[i];
      }
    }
  };

  loadA();                             // prologue: tile 0 in flight
  loadB();

  for (int kt = 0; kt < NT; ++kt) {
    __syncthreads();                   // barrier-1: vm drain cheap (loads had MFMA-phase cover)
    writeA();
    writeB();
    __syncthreads();                   // barrier-2: lgkm (ds_writes) only -- no fresh VM ops
    if (kt + 1 < NT) {                 // issue tile kt+1: full MFMA phase of latency cover
      loadA();
      loadB();
    }
#pragma unroll
    for (int kk = 0; kk < 2; ++kk) {
      bf16x8 af[4], bfr[4];
#pragma unroll
      for (int ms = 0; ms < 4; ++ms) {
        int row = wr * 64 + ms * 16 + lr;
        af[ms] = *(const bf16x8*)&As[sw(row, row * 64 + kk * 32 + lg * 8)];
      }
#pragma unroll
      for (int ns = 0; ns < 4; ++ns) {
        int row = wc * 64 + ns * 16 + lr;
        bfr[ns] = *(const bf16x8*)&Bs[sw(row, row * 64 + kk * 32 + lg * 8)];
      }
#pragma unroll
      for (int ms = 0; ms < 4; ++ms)
#pragma unroll
        for (int ns = 0; ns < 4; ++ns)
          acc[ms][ns] = mfma16(af[ms], bfr[ns], acc[ms][ns]);
    }
  }

  if (!OUT_F32 && blockIdx.z == 2) {
    // ---- V epilogue: transpose 128x128 tile via LDS -> Vt[bh][d][s] ----
    bf16* T = (bf16*)smem;             // 32 KB
    __syncthreads();
#pragma unroll
    for (int ms = 0; ms < 4; ++ms) {
#pragma unroll
      for (int ns = 0; ns < 4; ++ns) {
        int col = wc * 64 + ns * 16 + lr;                 // E-dim (d)
        int rowb = wr * 64 + ms * 16 + lg * 4;            // s-dim
        bf16x4 hv;
#pragma unroll
        for (int r = 0; r < 4; ++r) hv[r] = (bf16)acc[ms][ns][r];
        *(bf16x4*)&T[col * 128 + (rowb ^ ((col & 7) << 3))] = hv;
      }
    }
    __syncthreads();
    int chunk = tid & 15, dl0 = tid >> 4;
#pragma unroll
    for (int pass = 0; pass < 8; ++pass) {
      int dl = pass * 16 + dl0;
      bf16x8 v = *(const bf16x8*)&T[dl * 128 + ((chunk * 8) ^ ((dl & 7) << 3))];
      int colg = bcol + dl;
      int bh2 = (brow >> 11) * 16 + (colg >> 6);
      int d = colg & 63;
      int s0 = (brow & 2047) + chunk * 8;
      *(bf16x8*)((bf16*)g.O + ((size_t)bh2 * 64 + d) * (size_t)S_ + s0) = v;
    }
    return;
  }

#pragma unroll
  for (int ms = 0; ms < 4; ++ms) {
#pragma unroll
    for (int ns = 0; ns < 4; ++ns) {
#pragma unroll
      for (int r = 0; r < 4; ++r) {
        int row = brow + wr * 64 + ms * 16 + lg * 4 + r;
        int col = bcol + wc * 64 + ns * 16 + lr;
        if constexpr (OUT_F32) ((float*)g.O)[(size_t)row * E_ + col] = acc[ms][ns][r];
        else                   ((bf16*)g.O)[(size_t)row * E_ + col] = (bf16)acc[ms][ns][r];
      }
    }
  }
}

// ---------------- flash attention: 8-wave QBLK=256, shared K/V staging (R13, frozen) ----------------
// grid(512) x 512 threads: xcd=raw&7; bh = xcd*8 + (slot>>3); qblk = slot&7
__global__ __launch_bounds__(512, 4)
void attn_kernel(const bf16* __restrict__ Q, const bf16* __restrict__ K,
                 const bf16* __restrict__ Vt, const uint2* __restrict__ mbt,
                 bf16* __restrict__ alpha) {
  const int raw = blockIdx.x;
  const int xcd = raw & 7, slot = raw >> 3;
  const int bh = xcd * 8 + (slot >> 3), qblk = slot & 7;
  const int b = bh >> 4, h = bh & 15;
  const int tid = threadIdx.x, wv = tid >> 6, l = tid & 63;
  const int ln = l & 31, hi = l >> 5;
  const int qw = qblk * 256 + wv * 32;
  const int sr = l >> 3, sc8 = l & 7;
  const int g = (ln & 7) ^ (ln >> 3);      // read-side row-hash

  __shared__ bf16 Ks[2][64 * 64];          // [k][d], swizzled chunks (128B rows)
  __shared__ bf16 Vs[2][64 * 64];          // [d][k], swizzled chunks (128B rows)

  // Q fragments: qreg[dc] = Q[qw+ln][dc*16+hi*8 ..+8]
  bf16x8 qreg[4];
#pragma unroll
  for (int dc = 0; dc < 4; ++dc)
    qreg[dc] = *(const bf16x8*)(Q + (size_t)(b * S_ + qw + ln) * E_ + h * 64 + dc * 16 + hi * 8);

  bf16x8 ones;
#pragma unroll
  for (int j = 0; j < 8; ++j) ones[j] = (bf16)1.0f;

  f32x16 o[2] = {};                        // o[dt]
  f32x16 lacc = {};                        // row-sums of P

  // staging: each of 8 waves stages 8 rows of K and 8 of Vt.
  // global f(row) = (row&7)^((row>>3)&7); row = wv*8+sr -> f = sr ^ wv
  const int c0 = (sc8 ^ sr ^ wv) * 8;
  const bf16* kp = K + (size_t)(b * S_ + wv * 8 + sr) * E_ + h * 64 + c0;
  const bf16* vp = Vt + ((size_t)bh * 64 + wv * 8 + sr) * S_ + c0;
  const uint2* mrow = mbt + ((size_t)b << 16) + qw + ln;

  auto stage = [&](int buf) {
    gl_lds16(kp, Ks[buf] + (wv * 8) * 64);
    gl_lds16(vp, Vs[buf] + (wv * 8) * 64);
    kp += (size_t)64 * E_;
    vp += 64;
  };

  stage(0);
  __syncthreads();

  for (int kt = 0; kt < 32; ++kt) {
    const int cur = kt & 1;
    if (kt < 31) stage(cur ^ 1);

    // ---- QK^T: sc[ct] = S^T[k = kt*64+ct*32+crow][q = qw+ln] ----
    f32x16 sc[2] = {};
    __builtin_amdgcn_s_setprio(1);
#pragma unroll
    for (int ct = 0; ct < 2; ++ct) {
#pragma unroll
      for (int dc = 0; dc < 4; ++dc) {
        int row = ct * 32 + ln;
        int c = (dc * 2 + hi) ^ g ^ (ct * 4);
        bf16x8 kf = *(const bf16x8*)&Ks[cur][row * 64 + c * 8];
        sc[ct] = mfma32(kf, qreg[dc], sc[ct]);
      }
    }
    __builtin_amdgcn_s_setprio(0);

    // ---- mask: one coalesced uint2, pre-ANDed with padding ----
    uint2 mv = *mrow;
    mrow += 2048;
    uint32_t mq[2];
    mq[0] = mv.x >> (hi * 4);
    mq[1] = mv.y >> (hi * 4);

    // ---- p = exp2(s), masked via sbfe+and; pack to bf16 ----
    uint32_t up[16];
#pragma unroll
    for (int ct = 0; ct < 2; ++ct) {
      float p[16];
#pragma unroll
      for (int r = 0; r < 16; ++r) {
        const int rel = (r & 3) + 8 * (r >> 2);
        float pe = __builtin_amdgcn_exp2f(sc[ct][r]);
        uint32_t keep = (uint32_t)__builtin_amdgcn_sbfe(mq[ct], rel, 1);
        p[r] = __builtin_bit_cast(float, __builtin_bit_cast(uint32_t, pe) & keep);
      }
#pragma unroll
      for (int j = 0; j < 8; ++j)
        up[ct * 8 + j] = cvtpk(p[2 * j], p[2 * j + 1]);
    }

    // ---- PV + l-sum via permlane32_swap fragments ----
#pragma unroll
    for (int kc = 0; kc < 4; ++kc) {
      const int ct = kc >> 1, base = ct * 8 + (kc & 1) * 4;
      plswap(up[base + 0], up[base + 2]);
      plswap(up[base + 1], up[base + 3]);
      u32x4 w = {up[base + 0], up[base + 1], up[base + 2], up[base + 3]};
      bf16x8 pf = __builtin_bit_cast(bf16x8, w);
      __builtin_amdgcn_s_setprio(1);
#pragma unroll
      for (int dt = 0; dt < 2; ++dt) {
        int row = dt * 32 + ln;
        int c = (kc * 2 + hi) ^ g ^ (dt * 4);
        bf16x8 vf = *(const bf16x8*)&Vs[cur][row * 64 + c * 8];
        o[dt] = mfma32(vf, pf, o[dt]);
      }
      lacc = mfma32(ones, pf, lacc);
      __builtin_amdgcn_s_setprio(0);
    }
    __syncthreads();
  }

  // ---- epilogue: alpha = o / l ----
  float inv = 1.0f / lacc[0];
  size_t qoff = (size_t)(b * S_ + qw + ln) * E_ + h * 64;
#pragma unroll
  for (int dt = 0; dt < 2; ++dt) {
#pragma unroll
    for (int rg = 0; rg < 4; ++rg) {
      bf16x4 ov;
#pragma unroll
      for (int j = 0; j < 4; ++j) ov[j] = (bf16)(o[dt][rg * 4 + j] * inv);
      *(bf16x4*)(alpha + qoff + dt * 32 + rg * 8 + hi * 4) = ov;
    }
  }
}

// ---------------- launch ----------------
extern "C" void kernel_launch(void* const* d_in, const int* in_sizes, int n_in,
                              void* d_out, int out_size, void* d_ws, size_t ws_size,
                              hipStream_t stream) {
  const float* query = (const float*)d_in[0];
  const float* key_t = (const float*)d_in[1];
  const float* value = (const float*)d_in[2];
  const int*   mask  = (const int*)d_in[3];
  const int*   pad   = (const int*)d_in[4];
  const float* Wq    = (const float*)d_in[5];
  const float* Wk    = (const float*)d_in[6];
  const float* Wv    = (const float*)d_in[7];
  const float* Wo    = (const float*)d_in[8];

  char* ws = (char*)d_ws;
  bf16* alpha = (bf16*)ws;                              // 16M
  bf16* Wb    = (bf16*)(ws + ((size_t)16 << 20));       // 8M
  bf16* QKV   = (bf16*)(ws + ((size_t)24 << 20));       // 48M: Q, K, Vt
  uint32_t* mbits = (uint32_t*)(ws + ((size_t)72 << 20));
  uint32_t* pbits = mbits + (size_t)S_ * 64;
  uint2*    mbt   = (uint2*)(ws + ((size_t)73 << 20));  // 2M [b][kt][q]

  const size_t AM = 8192ull * 1024ull;
  const size_t WM = 1024ull * 1024ull;
  bf16* Vt = QKV + 2 * AM;

  pack_mask_kernel<<<512, 256, 0, stream>>>(mask, mbits);
  pack_pad_kernel<<<1, 256, 0, stream>>>(pad, pbits);
  expand_mask<<<1024, 256, 0, stream>>>(mbits, pbits, mbt);

  const float qscale = 0.17677669529663687f;            // 1024^-0.25
  const float log2e  = 1.4426950408889634f;
  cvt_w<<<dim3(512, 1, 4), 256, 0, stream>>>(Wq, Wk, Wv, Wo, Wb, qscale * log2e, qscale);

  GA gq{query, Wb,          QKV};
  GA gk{key_t, Wb + WM,     QKV + AM};
  GA gv{value, Wb + 2 * WM, Vt};
  gemm_bf<true, false><<<dim3(512, 1, 3), 256, 0, stream>>>(gq, gk, gv);

  attn_kernel<<<512, 512, 0, stream>>>(QKV, QKV + AM, Vt, mbt, alpha);

  GA go{alpha, Wb + 3 * WM, d_out};
  gemm_bf<false, true><<<dim3(512, 1, 1), 256, 0, stream>>>(go, go, go);
}

// Round 15
// 198.991 us; speedup vs baseline: 1.2239x; 1.2239x over previous
//
#include <hip/hip_runtime.h>
#include <stdint.h>

#define B_  4
#define S_  2048
#define E_  1024
#define H_  16
#define D_  64

typedef __bf16 bf16;
typedef __bf16 bf16x4 __attribute__((ext_vector_type(4)));
typedef __bf16 bf16x8 __attribute__((ext_vector_type(8)));
typedef float  f32x4 __attribute__((ext_vector_type(4)));
typedef float  f32x16 __attribute__((ext_vector_type(16)));
typedef uint32_t u32x4 __attribute__((ext_vector_type(4)));

__device__ __forceinline__ f32x4 mfma16(bf16x8 a, bf16x8 b, f32x4 c) {
  return __builtin_amdgcn_mfma_f32_16x16x32_bf16(a, b, c, 0, 0, 0);
}
__device__ __forceinline__ f32x16 mfma32(bf16x8 a, bf16x8 b, f32x16 c) {
  return __builtin_amdgcn_mfma_f32_32x32x16_bf16(a, b, c, 0, 0, 0);
}

// bf16 swizzle (128B rows, 8 chunks of 8 bf16): chunk ^= row&7 (halfword units)
__device__ __forceinline__ int sw(int row, int idx) { return idx ^ ((row & 7) << 3); }

__device__ __forceinline__ void gl_lds16(const void* g, void* l) {
  __builtin_amdgcn_global_load_lds(
      (const __attribute__((address_space(1))) void*)g,
      (__attribute__((address_space(3))) void*)l, 16, 0, 0);
}

__device__ __forceinline__ uint32_t cvtpk(float lo, float hi) {
  uint32_t r;
  asm("v_cvt_pk_bf16_f32 %0, %1, %2" : "=v"(r) : "v"(lo), "v"(hi));
  return r;
}
__device__ __forceinline__ void plswap(uint32_t& a, uint32_t& b) {
  asm("v_permlane32_swap_b32 %0, %1" : "+v"(a), "+v"(b));
}

__device__ __forceinline__ uint32_t pack32(const int* __restrict__ p) {
  uint32_t bits = 0;
#pragma unroll
  for (int j = 0; j < 32; j += 4) {
    int4 v = *(const int4*)(p + j);
    bits |= (v.x != 0 ? 1u : 0u) << (j + 0);
    bits |= (v.y != 0 ? 1u : 0u) << (j + 1);
    bits |= (v.z != 0 ? 1u : 0u) << (j + 2);
    bits |= (v.w != 0 ? 1u : 0u) << (j + 3);
  }
  return bits;
}

// ---------------- prep1: pack mask bits (blocks 0..511) + pad bits (block 512) ----------------
__global__ __launch_bounds__(256)
void prep1(const int* __restrict__ mask, const int* __restrict__ pad,
           uint32_t* __restrict__ mbits, uint32_t* __restrict__ pbits) {
  if (blockIdx.x < 512) {
    int idx = blockIdx.x * 256 + threadIdx.x;   // 2048*64 words
    int q = idx >> 6, w = idx & 63;
    mbits[idx] = pack32(mask + q * S_ + w * 32);
  } else {
    int idx = threadIdx.x;                      // 4*64 words
    int b = idx >> 6, w = idx & 63;
    pbits[idx] = pack32(pad + b * S_ + w * 32);
  }
}

// ---------------- prep2: expand_mask (blocks 0..1023) + cvt_w (blocks 1024..3071) ----------------
// mbt[b][kt][q] = {mbits[q][2kt]&pad, mbits[q][2kt+1]&pad}
__global__ __launch_bounds__(256)
void prep2(const uint32_t* __restrict__ mbits, const uint32_t* __restrict__ pbits,
           uint2* __restrict__ mbt,
           const float* __restrict__ w0, const float* __restrict__ w1,
           const float* __restrict__ w2, const float* __restrict__ w3,
           bf16* __restrict__ wout, float sq, float sk) {
  int id = blockIdx.x;
  if (id < 1024) {
    int idx = id * 256 + threadIdx.x;           // b(4) x kt(32) x q(2048)
    int q = idx & 2047;
    int kt = (idx >> 11) & 31;
    int b = idx >> 16;
    uint2 r;
    r.x = mbits[q * 64 + kt * 2 + 0] & pbits[b * 64 + kt * 2 + 0];
    r.y = mbits[q * 64 + kt * 2 + 1] & pbits[b * 64 + kt * 2 + 1];
    mbt[idx] = r;
  } else {
    int zid = id - 1024;
    int z = zid >> 9, xb = zid & 511;
    const float* src = z == 0 ? w0 : (z == 1 ? w1 : (z == 2 ? w2 : w3));
    float s = (z == 0) ? sq : ((z == 1) ? sk : 1.0f);
    size_t i = ((size_t)xb * 256 + threadIdx.x) * 8;
    float4 a = *(const float4*)(src + i);
    float4 b = *(const float4*)(src + i + 4);
    bf16x8 o;
    o[0] = (bf16)(a.x * s); o[1] = (bf16)(a.y * s); o[2] = (bf16)(a.z * s); o[3] = (bf16)(a.w * s);
    o[4] = (bf16)(b.x * s); o[5] = (bf16)(b.y * s); o[6] = (bf16)(b.z * s); o[7] = (bf16)(b.w * s);
    *(bf16x8*)(wout + (size_t)z * (1024ull * 1024ull) + i) = o;
  }
}

// ---------------- GEMM: C = A @ W^T (R10/R13 structure, frozen) ----------------
// A_F32: A reg-staged (global fp32 -> cvtpk -> ds_write bf16), loads issued one
//        K-step early so HBM latency hides under the MFMA phase. B via gl_lds.
// grid.x = 512 flat, XCD-chunked: xcd k owns row panels [k*8,(k+1)*8) x 8 col panels.
struct GA { const void* A; const bf16* W; void* O; };

template<bool A_F32, bool OUT_F32>
__global__ __launch_bounds__(256, 4)
void gemm_bf(GA g0, GA g1, GA g2) {
  GA g = (blockIdx.z == 0) ? g0 : ((blockIdx.z == 1) ? g1 : g2);
  const int id = blockIdx.x;
  const int brow = ((id & 7) * 8 + (id >> 6)) * 128;
  const int bcol = ((id >> 3) & 7) * 128;
  const int tid = threadIdx.x;
  const int l = tid & 63, wv = tid >> 6;
  const int lg = l >> 4, lr = l & 15;
  const int wr = wv >> 1, wc = wv & 1;
  const int sr = l >> 3, sc8 = l & 7;

  __shared__ __align__(16) char smem[32768];
  bf16* As = (bf16*)smem;              // 128 x 64 bf16, swizzled
  bf16* Bs = (bf16*)(smem + 16384);    // 128 x 64 bf16, swizzled

  f32x4 acc[4][4] = {};

  const bf16* Bb = g.W + (size_t)(bcol + wv * 32 + sr) * E_ + (size_t)(sc8 ^ sr) * 8;
  bf16* lb = Bs + (wv * 32) * 64;

  const bf16* Abb = nullptr;
  const float* Ap = nullptr;
  f32x4 a0[4], a1[4];
  if constexpr (A_F32) {
    Ap = (const float*)g.A + (size_t)(brow + wv * 32 + sr) * E_ + sc8 * 8;
  } else {
    Abb = (const bf16*)g.A + (size_t)(brow + wv * 32 + sr) * E_ + (size_t)(sc8 ^ sr) * 8;
  }

  auto loadA = [&]() {
#pragma unroll
    for (int i = 0; i < 4; ++i) {
      const float* p = Ap + (size_t)(8 * i) * E_;
      a0[i] = *(const f32x4*)p;
      a1[i] = *(const f32x4*)(p + 4);
    }
    Ap += 64;
  };
  auto writeA = [&]() {
#pragma unroll
    for (int i = 0; i < 4; ++i) {
      int row = wv * 32 + sr + 8 * i;
      u32x4 pk = { cvtpk(a0[i][0], a0[i][1]), cvtpk(a0[i][2], a0[i][3]),
                   cvtpk(a1[i][0], a1[i][1]), cvtpk(a1[i][2], a1[i][3]) };
      *(bf16x8*)&As[sw(row, row * 64 + sc8 * 8)] = __builtin_bit_cast(bf16x8, pk);
    }
  };

  if constexpr (A_F32) loadA();

  for (int kt = 0; kt < E_ / 64; ++kt) {
    __syncthreads();
    if constexpr (A_F32) {
      writeA();
    } else {
      bf16* la = As + (wv * 32) * 64;
      const bf16* a = Abb + kt * 64;
#pragma unroll
      for (int i = 0; i < 4; ++i)
        gl_lds16(a + (size_t)i * 8 * E_, la + i * 8 * 64);
    }
    {
      const bf16* b = Bb + kt * 64;
#pragma unroll
      for (int i = 0; i < 4; ++i)
        gl_lds16(b + (size_t)i * 8 * E_, lb + i * 8 * 64);
    }
    __syncthreads();
    if constexpr (A_F32) {
      if (kt + 1 < E_ / 64) loadA();
    }
#pragma unroll
    for (int kk = 0; kk < 2; ++kk) {
      bf16x8 af[4], bfr[4];
#pragma unroll
      for (int ms = 0; ms < 4; ++ms) {
        int row = wr * 64 + ms * 16 + lr;
        af[ms] = *(const bf16x8*)&As[sw(row, row * 64 + kk * 32 + lg * 8)];
      }
#pragma unroll
      for (int ns = 0; ns < 4; ++ns) {
        int row = wc * 64 + ns * 16 + lr;
        bfr[ns] = *(const bf16x8*)&Bs[sw(row, row * 64 + kk * 32 + lg * 8)];
      }
#pragma unroll
      for (int ms = 0; ms < 4; ++ms)
#pragma unroll
        for (int ns = 0; ns < 4; ++ns)
          acc[ms][ns] = mfma16(af[ms], bfr[ns], acc[ms][ns]);
    }
  }

  if (!OUT_F32 && blockIdx.z == 2) {
    // ---- V epilogue: transpose 128x128 tile via LDS -> Vt[bh][d][s] ----
    bf16* T = (bf16*)smem;             // 32 KB
    __syncthreads();
#pragma unroll
    for (int ms = 0; ms < 4; ++ms) {
#pragma unroll
      for (int ns = 0; ns < 4; ++ns) {
        int col = wc * 64 + ns * 16 + lr;                 // E-dim (d)
        int rowb = wr * 64 + ms * 16 + lg * 4;            // s-dim
        bf16x4 hv;
#pragma unroll
        for (int r = 0; r < 4; ++r) hv[r] = (bf16)acc[ms][ns][r];
        *(bf16x4*)&T[col * 128 + (rowb ^ ((col & 7) << 3))] = hv;
      }
    }
    __syncthreads();
    int chunk = tid & 15, dl0 = tid >> 4;
#pragma unroll
    for (int pass = 0; pass < 8; ++pass) {
      int dl = pass * 16 + dl0;
      bf16x8 v = *(const bf16x8*)&T[dl * 128 + ((chunk * 8) ^ ((dl & 7) << 3))];
      int colg = bcol + dl;
      int bh2 = (brow >> 11) * 16 + (colg >> 6);
      int d = colg & 63;
      int s0 = (brow & 2047) + chunk * 8;
      *(bf16x8*)((bf16*)g.O + ((size_t)bh2 * 64 + d) * (size_t)S_ + s0) = v;
    }
    return;
  }

#pragma unroll
  for (int ms = 0; ms < 4; ++ms) {
#pragma unroll
    for (int ns = 0; ns < 4; ++ns) {
#pragma unroll
      for (int r = 0; r < 4; ++r) {
        int row = brow + wr * 64 + ms * 16 + lg * 4 + r;
        int col = bcol + wc * 64 + ns * 16 + lr;
        if constexpr (OUT_F32) ((float*)g.O)[(size_t)row * E_ + col] = acc[ms][ns][r];
        else                   ((bf16*)g.O)[(size_t)row * E_ + col] = (bf16)acc[ms][ns][r];
      }
    }
  }
}

// ---------------- flash attention: 8-wave QBLK=256, shared K/V staging (R13, frozen) ----------------
// grid(512) x 512 threads: xcd=raw&7; bh = xcd*8 + (slot>>3); qblk = slot&7
__global__ __launch_bounds__(512, 4)
void attn_kernel(const bf16* __restrict__ Q, const bf16* __restrict__ K,
                 const bf16* __restrict__ Vt, const uint2* __restrict__ mbt,
                 bf16* __restrict__ alpha) {
  const int raw = blockIdx.x;
  const int xcd = raw & 7, slot = raw >> 3;
  const int bh = xcd * 8 + (slot >> 3), qblk = slot & 7;
  const int b = bh >> 4, h = bh & 15;
  const int tid = threadIdx.x, wv = tid >> 6, l = tid & 63;
  const int ln = l & 31, hi = l >> 5;
  const int qw = qblk * 256 + wv * 32;
  const int sr = l >> 3, sc8 = l & 7;
  const int g = (ln & 7) ^ (ln >> 3);      // read-side row-hash

  __shared__ bf16 Ks[2][64 * 64];          // [k][d], swizzled chunks (128B rows)
  __shared__ bf16 Vs[2][64 * 64];          // [d][k], swizzled chunks (128B rows)

  // Q fragments: qreg[dc] = Q[qw+ln][dc*16+hi*8 ..+8]
  bf16x8 qreg[4];
#pragma unroll
  for (int dc = 0; dc < 4; ++dc)
    qreg[dc] = *(const bf16x8*)(Q + (size_t)(b * S_ + qw + ln) * E_ + h * 64 + dc * 16 + hi * 8);

  bf16x8 ones;
#pragma unroll
  for (int j = 0; j < 8; ++j) ones[j] = (bf16)1.0f;

  f32x16 o[2] = {};                        // o[dt]
  f32x16 lacc = {};                        // row-sums of P

  // staging: each of 8 waves stages 8 rows of K and 8 of Vt.
  // global f(row) = (row&7)^((row>>3)&7); row = wv*8+sr -> f = sr ^ wv
  const int c0 = (sc8 ^ sr ^ wv) * 8;
  const bf16* kp = K + (size_t)(b * S_ + wv * 8 + sr) * E_ + h * 64 + c0;
  const bf16* vp = Vt + ((size_t)bh * 64 + wv * 8 + sr) * S_ + c0;
  const uint2* mrow = mbt + ((size_t)b << 16) + qw + ln;

  auto stage = [&](int buf) {
    gl_lds16(kp, Ks[buf] + (wv * 8) * 64);
    gl_lds16(vp, Vs[buf] + (wv * 8) * 64);
    kp += (size_t)64 * E_;
    vp += 64;
  };

  stage(0);
  __syncthreads();

  for (int kt = 0; kt < 32; ++kt) {
    const int cur = kt & 1;
    if (kt < 31) stage(cur ^ 1);

    // ---- QK^T: sc[ct] = S^T[k = kt*64+ct*32+crow][q = qw+ln] ----
    f32x16 sc[2] = {};
    __builtin_amdgcn_s_setprio(1);
#pragma unroll
    for (int ct = 0; ct < 2; ++ct) {
#pragma unroll
      for (int dc = 0; dc < 4; ++dc) {
        int row = ct * 32 + ln;
        int c = (dc * 2 + hi) ^ g ^ (ct * 4);
        bf16x8 kf = *(const bf16x8*)&Ks[cur][row * 64 + c * 8];
        sc[ct] = mfma32(kf, qreg[dc], sc[ct]);
      }
    }
    __builtin_amdgcn_s_setprio(0);

    // ---- mask: one coalesced uint2, pre-ANDed with padding ----
    uint2 mv = *mrow;
    mrow += 2048;
    uint32_t mq[2];
    mq[0] = mv.x >> (hi * 4);
    mq[1] = mv.y >> (hi * 4);

    // ---- p = exp2(s), masked via sbfe+and; pack to bf16 ----
    uint32_t up[16];
#pragma unroll
    for (int ct = 0; ct < 2; ++ct) {
      float p[16];
#pragma unroll
      for (int r = 0; r < 16; ++r) {
        const int rel = (r & 3) + 8 * (r >> 2);
        float pe = __builtin_amdgcn_exp2f(sc[ct][r]);
        uint32_t keep = (uint32_t)__builtin_amdgcn_sbfe(mq[ct], rel, 1);
        p[r] = __builtin_bit_cast(float, __builtin_bit_cast(uint32_t, pe) & keep);
      }
#pragma unroll
      for (int j = 0; j < 8; ++j)
        up[ct * 8 + j] = cvtpk(p[2 * j], p[2 * j + 1]);
    }

    // ---- PV + l-sum via permlane32_swap fragments ----
#pragma unroll
    for (int kc = 0; kc < 4; ++kc) {
      const int ct = kc >> 1, base = ct * 8 + (kc & 1) * 4;
      plswap(up[base + 0], up[base + 2]);
      plswap(up[base + 1], up[base + 3]);
      u32x4 w = {up[base + 0], up[base + 1], up[base + 2], up[base + 3]};
      bf16x8 pf = __builtin_bit_cast(bf16x8, w);
      __builtin_amdgcn_s_setprio(1);
#pragma unroll
      for (int dt = 0; dt < 2; ++dt) {
        int row = dt * 32 + ln;
        int c = (kc * 2 + hi) ^ g ^ (dt * 4);
        bf16x8 vf = *(const bf16x8*)&Vs[cur][row * 64 + c * 8];
        o[dt] = mfma32(vf, pf, o[dt]);
      }
      lacc = mfma32(ones, pf, lacc);
      __builtin_amdgcn_s_setprio(0);
    }
    __syncthreads();
  }

  // ---- epilogue: alpha = o / l ----
  float inv = 1.0f / lacc[0];
  size_t qoff = (size_t)(b * S_ + qw + ln) * E_ + h * 64;
#pragma unroll
  for (int dt = 0; dt < 2; ++dt) {
#pragma unroll
    for (int rg = 0; rg < 4; ++rg) {
      bf16x4 ov;
#pragma unroll
      for (int j = 0; j < 4; ++j) ov[j] = (bf16)(o[dt][rg * 4 + j] * inv);
      *(bf16x4*)(alpha + qoff + dt * 32 + rg * 8 + hi * 4) = ov;
    }
  }
}

// ---------------- launch ----------------
extern "C" void kernel_launch(void* const* d_in, const int* in_sizes, int n_in,
                              void* d_out, int out_size, void* d_ws, size_t ws_size,
                              hipStream_t stream) {
  const float* query = (const float*)d_in[0];
  const float* key_t = (const float*)d_in[1];
  const float* value = (const float*)d_in[2];
  const int*   mask  = (const int*)d_in[3];
  const int*   pad   = (const int*)d_in[4];
  const float* Wq    = (const float*)d_in[5];
  const float* Wk    = (const float*)d_in[6];
  const float* Wv    = (const float*)d_in[7];
  const float* Wo    = (const float*)d_in[8];

  char* ws = (char*)d_ws;
  bf16* alpha = (bf16*)ws;                              // 16M
  bf16* Wb    = (bf16*)(ws + ((size_t)16 << 20));       // 8M
  bf16* QKV   = (bf16*)(ws + ((size_t)24 << 20));       // 48M: Q, K, Vt
  uint32_t* mbits = (uint32_t*)(ws + ((size_t)72 << 20));
  uint32_t* pbits = mbits + (size_t)S_ * 64;
  uint2*    mbt   = (uint2*)(ws + ((size_t)73 << 20));  // 2M [b][kt][q]

  const size_t AM = 8192ull * 1024ull;
  const size_t WM = 1024ull * 1024ull;
  bf16* Vt = QKV + 2 * AM;

  const float qscale = 0.17677669529663687f;            // 1024^-0.25
  const float log2e  = 1.4426950408889634f;

  prep1<<<513, 256, 0, stream>>>(mask, pad, mbits, pbits);
  prep2<<<3072, 256, 0, stream>>>(mbits, pbits, mbt, Wq, Wk, Wv, Wo, Wb,
                                  qscale * log2e, qscale);

  GA gq{query, Wb,          QKV};
  GA gk{key_t, Wb + WM,     QKV + AM};
  GA gv{value, Wb + 2 * WM, Vt};
  gemm_bf<true, false><<<dim3(512, 1, 3), 256, 0, stream>>>(gq, gk, gv);

  attn_kernel<<<512, 512, 0, stream>>>(QKV, QKV + AM, Vt, mbt, alpha);

  GA go{alpha, Wb + 3 * WM, d_out};
  gemm_bf<false, true><<<dim3(512, 1, 1), 256, 0, stream>>>(go, go, go);
}